// Round 1
// baseline (700.570 us; speedup 1.0000x reference)
//
#include <hip/hip_runtime.h>

#define NN 50000
#define NE 500000
#define HID 128

// ---------------------------------------------------------------------------
// GEMM: out[wq][n][128] = X[n][:] @ W_wq + b_wq   for wq in {q,k,v,skip}
// grid = (ceil(NN/64), 8); block = 256. ntile selects weight (ntile>>1) and
// 64-col half (ntile&1). 64x64 tile, 4x4 per thread, full K=128 staged in LDS.
// Xs is XOR-swizzled (k ^= (row&7)<<2) so inner-loop reads are conflict-free.
// ---------------------------------------------------------------------------
__global__ __launch_bounds__(256) void gemm_qkvs(
    const float* __restrict__ X,
    const float* __restrict__ Wq, const float* __restrict__ bq,
    const float* __restrict__ Wk, const float* __restrict__ bk,
    const float* __restrict__ Wv, const float* __restrict__ bv,
    const float* __restrict__ Wsk, const float* __restrict__ bsk,
    float* __restrict__ qkvs)
{
    __shared__ float Xs[64][128];
    __shared__ float Wt[128][64];
    const int mtile = blockIdx.x, ntile = blockIdx.y;
    const int wq = ntile >> 1;
    const float* Wsel = (wq == 0) ? Wq : (wq == 1) ? Wk : (wq == 2) ? Wv : Wsk;
    const float* bsel = (wq == 0) ? bq : (wq == 1) ? bk : (wq == 2) ? bv : bsk;
    const int colbase = (ntile & 1) * 64;
    const int Mbase = mtile * 64;
    const int tid = threadIdx.x;

    // stage W tile [128][64]
    #pragma unroll
    for (int l = 0; l < 8; ++l) {
        int lin = l * 256 + tid;
        int k  = lin >> 4;
        int c4 = (lin & 15) << 2;
        *reinterpret_cast<float4*>(&Wt[k][c4]) =
            *reinterpret_cast<const float4*>(&Wsel[k * HID + colbase + c4]);
    }
    // stage X tile [64][128], swizzled
    #pragma unroll
    for (int l = 0; l < 8; ++l) {
        int lin = l * 256 + tid;
        int row = lin >> 5;
        int k4  = (lin & 31) << 2;
        int rowg = Mbase + row; if (rowg >= NN) rowg = NN - 1;
        int ksw = k4 ^ ((row & 7) << 2);
        *reinterpret_cast<float4*>(&Xs[row][ksw]) =
            *reinterpret_cast<const float4*>(&X[rowg * HID + k4]);
    }
    __syncthreads();

    const int tc = tid & 15, tr = tid >> 4;
    const int m0 = tr * 4, n0 = tc * 4;
    float acc[4][4] = {};
    #pragma unroll 8
    for (int k = 0; k < 128; ++k) {
        float4 wv = *reinterpret_cast<const float4*>(&Wt[k][n0]);
        const float* wp = reinterpret_cast<const float*>(&wv);
        float xv[4];
        #pragma unroll
        for (int i = 0; i < 4; ++i) {
            int m = m0 + i;
            xv[i] = Xs[m][k ^ ((m & 7) << 2)];
        }
        #pragma unroll
        for (int i = 0; i < 4; ++i)
            #pragma unroll
            for (int j = 0; j < 4; ++j)
                acc[i][j] += xv[i] * wp[j];
    }

    #pragma unroll
    for (int i = 0; i < 4; ++i) {
        int row = Mbase + m0 + i;
        if (row < NN) {
            float4 o;
            float* op = reinterpret_cast<float*>(&o);
            #pragma unroll
            for (int j = 0; j < 4; ++j)
                op[j] = acc[i][j] + bsel[colbase + n0 + j];
            *reinterpret_cast<float4*>(
                &qkvs[((size_t)wq * NN + row) * HID + colbase + n0]) = o;
        }
    }
}

// ---------------------------------------------------------------------------
// CSR build (per call; shared by both layers)
// ---------------------------------------------------------------------------
__global__ void zero_i32(int* __restrict__ p, int n)
{
    int i = blockIdx.x * blockDim.x + threadIdx.x;
    if (i < n) p[i] = 0;
}

__global__ void hist_kernel(const int* __restrict__ dst, int* __restrict__ counts)
{
    int e = blockIdx.x * blockDim.x + threadIdx.x;
    if (e < NE) atomicAdd(&counts[dst[e]], 1);
}

__global__ __launch_bounds__(1024) void scan_kernel(
    const int* __restrict__ counts, int* __restrict__ offsets, int* __restrict__ cursor)
{
    __shared__ int part[1024];
    const int t = threadIdx.x;
    const int chunk = (NN + 1023) >> 10;               // 49
    const int beg = t * chunk;
    const int end = min(beg + chunk, NN);
    int s = 0;
    for (int i = beg; i < end; ++i) s += counts[i];
    part[t] = s;
    __syncthreads();
    for (int off = 1; off < 1024; off <<= 1) {
        int v = (t >= off) ? part[t - off] : 0;
        __syncthreads();
        part[t] += v;
        __syncthreads();
    }
    int run = (t > 0) ? part[t - 1] : 0;               // exclusive prefix
    for (int i = beg; i < end; ++i) {
        offsets[i] = run; cursor[i] = run; run += counts[i];
    }
    if (t == 1023) offsets[NN] = run;                  // == NE
}

__global__ void scatter_kernel(const int* __restrict__ src, const int* __restrict__ dst,
                               int* __restrict__ cursor, int* __restrict__ csr_src)
{
    int e = blockIdx.x * blockDim.x + threadIdx.x;
    if (e < NE) {
        int pos = atomicAdd(&cursor[dst[e]], 1);
        csr_src[pos] = src[e];
    }
}

// ---------------------------------------------------------------------------
// Node-parallel edge aggregation + softmax (no max-sub needed; fp32-safe) +
// skip + (layer2: residual) + PReLU, fused.
// block = 256 (2 nodes of 128 threads); thread t -> (h = t>>4, d = t&15).
// ---------------------------------------------------------------------------
template <int LAYER>
__global__ __launch_bounds__(256) void edge_aggregate(
    const float* __restrict__ qkvs,
    const int* __restrict__ offsets,
    const int* __restrict__ csr_src,
    const float* __restrict__ xres,     // layer2: original x; layer1: unused
    const float* __restrict__ prelu_w,
    float* __restrict__ out)
{
    const int local = threadIdx.x & 127;
    const int node  = blockIdx.x * 2 + (threadIdx.x >> 7);
    const float* Q = qkvs;
    const float* K = qkvs + (size_t)NN * HID;
    const float* V = qkvs + (size_t)2 * NN * HID;
    const float* S = qkvs + (size_t)3 * NN * HID;

    const float qv = Q[node * HID + local] * 0.25f;    // fold 1/sqrt(16)
    float acc = 0.f, den = 0.f;
    const int beg = offsets[node], end = offsets[node + 1];
    for (int i = beg; i < end; ++i) {
        int s = csr_src[i];
        float p = qv * K[s * HID + local];
        p += __shfl_xor(p, 1);
        p += __shfl_xor(p, 2);
        p += __shfl_xor(p, 4);
        p += __shfl_xor(p, 8);
        float w = __expf(p);
        den += w;
        acc += w * V[s * HID + local];
    }
    float r = (den > 0.f) ? acc / den : 0.f;
    r += S[node * HID + local];
    if (LAYER == 2) r += xres[node * HID + local];
    const float a = prelu_w[0];
    r = fmaxf(r, 0.f) + a * fminf(r, 0.f);
    out[node * HID + local] = r;
}

// ---------------------------------------------------------------------------
extern "C" void kernel_launch(void* const* d_in, const int* in_sizes, int n_in,
                              void* d_out, int out_size, void* d_ws, size_t ws_size,
                              hipStream_t stream)
{
    const float* x       = (const float*)d_in[0];
    const int*   ei      = (const int*)d_in[1];      // int32 [2][NE]
    const float* prelu_w = (const float*)d_in[2];
    const float* Wq1 = (const float*)d_in[3],  *bq1 = (const float*)d_in[4];
    const float* Wk1 = (const float*)d_in[5],  *bk1 = (const float*)d_in[6];
    const float* Wv1 = (const float*)d_in[7],  *bv1 = (const float*)d_in[8];
    const float* Ws1 = (const float*)d_in[9],  *bs1 = (const float*)d_in[10];
    const float* Wq2 = (const float*)d_in[11], *bq2 = (const float*)d_in[12];
    const float* Wk2 = (const float*)d_in[13], *bk2 = (const float*)d_in[14];
    const float* Wv2 = (const float*)d_in[15], *bv2 = (const float*)d_in[16];
    const float* Ws2 = (const float*)d_in[17], *bs2 = (const float*)d_in[18];

    // workspace layout (all 256B aligned)
    char* w = (char*)d_ws;
    size_t off = 0;
    auto alloc = [&](size_t bytes) { void* p = w + off; off += (bytes + 255) & ~(size_t)255; return p; };
    float* qkvs    = (float*)alloc((size_t)4 * NN * HID * sizeof(float)); // 102.4 MB
    float* x1      = (float*)alloc((size_t)NN * HID * sizeof(float));     // 25.6 MB
    int*   counts  = (int*)alloc(NN * sizeof(int));
    int*   offsets = (int*)alloc((NN + 1) * sizeof(int));
    int*   cursor  = (int*)alloc(NN * sizeof(int));
    int*   csr_src = (int*)alloc(NE * sizeof(int));
    (void)ws_size; (void)in_sizes; (void)n_in; (void)out_size;

    const int* srcIdx = ei;
    const int* dstIdx = ei + NE;

    // CSR build (shared by both layers)
    zero_i32<<<(NN + 255) / 256, 256, 0, stream>>>(counts, NN);
    hist_kernel<<<(NE + 255) / 256, 256, 0, stream>>>(dstIdx, counts);
    scan_kernel<<<1, 1024, 0, stream>>>(counts, offsets, cursor);
    scatter_kernel<<<(NE + 255) / 256, 256, 0, stream>>>(srcIdx, dstIdx, cursor, csr_src);

    dim3 ggemm((NN + 63) / 64, 8);

    // ---- layer 1 ----
    gemm_qkvs<<<ggemm, 256, 0, stream>>>(x, Wq1, bq1, Wk1, bk1, Wv1, bv1, Ws1, bs1, qkvs);
    edge_aggregate<1><<<NN / 2, 256, 0, stream>>>(qkvs, offsets, csr_src, nullptr, prelu_w, x1);

    // ---- layer 2 ----
    gemm_qkvs<<<ggemm, 256, 0, stream>>>(x1, Wq2, bq2, Wk2, bk2, Wv2, bv2, Ws2, bs2, qkvs);
    edge_aggregate<2><<<NN / 2, 256, 0, stream>>>(qkvs, offsets, csr_src, x, prelu_w, (float*)d_out);
}

// Round 2
// 298.357 us; speedup vs baseline: 2.3481x; 2.3481x over previous
//
#include <hip/hip_runtime.h>

#define NN 50000
#define NE 500000
#define HID 128

typedef __attribute__((ext_vector_type(8))) short short8;   // 8 bf16 = 4 VGPR
typedef __attribute__((ext_vector_type(4))) float f32x4;
typedef unsigned short ushort_t;

__device__ __forceinline__ float bf2f(ushort_t u) {
    union { float f; unsigned i; } x; x.i = ((unsigned)u) << 16; return x.f;
}
__device__ __forceinline__ ushort_t f2bf(float f) {
    union { float f; unsigned i; } x; x.f = f;
    unsigned r = x.i + 0x7FFFu + ((x.i >> 16) & 1u);   // RNE (no NaN inputs)
    return (ushort_t)(r >> 16);
}

// ---------------------------------------------------------------------------
// fp32 -> bf16 conversions
// ---------------------------------------------------------------------------
__global__ void convert_x(const float* __restrict__ X, ushort_t* __restrict__ Xb)
{
    int i = blockIdx.x * blockDim.x + threadIdx.x;       // one thread per 4 elems
    float4 v = *reinterpret_cast<const float4*>(X + (size_t)i * 4);
    ushort4 o;
    o.x = f2bf(v.x); o.y = f2bf(v.y); o.z = f2bf(v.z); o.w = f2bf(v.w);
    *reinterpret_cast<ushort4*>(Xb + (size_t)i * 4) = o;
}

// Bt[col][k] = W_(col/128)[k][col%128], bf16. 512x128.
__global__ void pack_w(const float* __restrict__ Wq, const float* __restrict__ Wk,
                       const float* __restrict__ Wv, const float* __restrict__ Ws,
                       ushort_t* __restrict__ Bt)
{
    int idx = blockIdx.x * 256 + threadIdx.x;            // 65536 total
    int col = idx >> 7;
    int k   = idx & 127;
    const float* W = (col < 128) ? Wq : (col < 256) ? Wk : (col < 384) ? Wv : Ws;
    Bt[idx] = f2bf(W[k * HID + (col & 127)]);
}

// ---------------------------------------------------------------------------
// MFMA GEMM: [NN][128]bf16 @ Bt-group -> Q/K/V bf16, S fp32 (+bias)
// grid (ceil(NN/64), 4); block 256 = 4 waves. LDS 48KB, XOR-swizzled tiles.
// ---------------------------------------------------------------------------
__global__ __launch_bounds__(256) void gemm_mfma(
    const ushort_t* __restrict__ Xb, const ushort_t* __restrict__ Bt,
    const float* __restrict__ bqp, const float* __restrict__ bkp,
    const float* __restrict__ bvp, const float* __restrict__ bsp,
    ushort_t* __restrict__ Qb, ushort_t* __restrict__ Kb,
    ushort_t* __restrict__ Vb, float* __restrict__ Sf)
{
    __shared__ ushort_t As[64 * 128];    // [row][k] swizzled, 16KB
    __shared__ ushort_t Bs[128 * 128];   // [col][k] swizzled, 32KB
    const int Mbase = blockIdx.x * 64;
    const int g = blockIdx.y;            // 0=q 1=k 2=v 3=skip
    const int tid = threadIdx.x;

    #pragma unroll
    for (int it = 0; it < 4; ++it) {                     // A: 1024 x 16B segs
        int lin = it * 256 + tid;
        int row = lin >> 4, s = lin & 15;
        int rg = Mbase + row; if (rg >= NN) rg = NN - 1;
        short8 v = *reinterpret_cast<const short8*>(Xb + (size_t)rg * HID + s * 8);
        *reinterpret_cast<short8*>((char*)As + row * 256 + ((s * 16) ^ ((row & 7) * 16))) = v;
    }
    #pragma unroll
    for (int it = 0; it < 8; ++it) {                     // B: 2048 x 16B segs
        int lin = it * 256 + tid;
        int col = lin >> 4, s = lin & 15;
        short8 v = *reinterpret_cast<const short8*>(Bt + (size_t)(g * 128 + col) * HID + s * 8);
        *reinterpret_cast<short8*>((char*)Bs + col * 256 + ((s * 16) ^ ((col & 7) * 16))) = v;
    }
    __syncthreads();

    const int lane = tid & 63, wave = tid >> 6;
    const int wrow = wave * 16;
    const int l15 = lane & 15;
    f32x4 acc[8] = {};
    #pragma unroll
    for (int kk = 0; kk < 4; ++kk) {
        int kbyte = kk * 64 + (lane >> 4) * 16;          // 16B of 8 bf16, contiguous K
        int ar = wrow + l15;
        short8 a = *reinterpret_cast<const short8*>(
            (const char*)As + ar * 256 + (kbyte ^ ((ar & 7) * 16)));
        #pragma unroll
        for (int nb = 0; nb < 8; ++nb) {
            int c = nb * 16 + l15;
            short8 b = *reinterpret_cast<const short8*>(
                (const char*)Bs + c * 256 + (kbyte ^ ((c & 7) * 16)));
            acc[nb] = __builtin_amdgcn_mfma_f32_16x16x32_bf16(a, b, acc[nb], 0, 0, 0);
        }
    }

    const float* bias = (g == 0) ? bqp : (g == 1) ? bkp : (g == 2) ? bvp : bsp;
    ushort_t* Ob = (g == 0) ? Qb : (g == 1) ? Kb : Vb;
    #pragma unroll
    for (int nb = 0; nb < 8; ++nb) {
        int cg = nb * 16 + l15;
        float bb = bias[cg];
        #pragma unroll
        for (int r = 0; r < 4; ++r) {
            int row = Mbase + wrow + (lane >> 4) * 4 + r;   // C/D: col=lane&15, row=(lane>>4)*4+reg
            if (row < NN) {
                float val = acc[nb][r] + bb;
                if (g == 3) Sf[(size_t)row * HID + cg] = val;
                else        Ob[(size_t)row * HID + cg] = f2bf(val);
            }
        }
    }
}

// ---------------------------------------------------------------------------
// CSR build
// ---------------------------------------------------------------------------
__global__ void zero_i32(int* __restrict__ p, int n)
{
    int i = blockIdx.x * blockDim.x + threadIdx.x;
    if (i < n) p[i] = 0;
}

__global__ void hist_kernel(const int* __restrict__ dst, int* __restrict__ counts)
{
    int e = blockIdx.x * blockDim.x + threadIdx.x;
    if (e < NE) atomicAdd(&counts[dst[e]], 1);
}

#define SCAN_B 196   // ceil(NN/256)

__global__ __launch_bounds__(256) void block_sums(const int* __restrict__ counts,
                                                  int* __restrict__ bsum)
{
    int i = blockIdx.x * 256 + threadIdx.x;
    int v = (i < NN) ? counts[i] : 0;
    #pragma unroll
    for (int o = 1; o < 64; o <<= 1) v += __shfl_xor(v, o);
    __shared__ int ws[4];
    if ((threadIdx.x & 63) == 0) ws[threadIdx.x >> 6] = v;
    __syncthreads();
    if (threadIdx.x == 0) bsum[blockIdx.x] = ws[0] + ws[1] + ws[2] + ws[3];
}

__global__ __launch_bounds__(256) void scan_bsums(const int* __restrict__ bsum,
                                                  int* __restrict__ bbase)
{
    __shared__ int sh[256];
    int t = threadIdx.x;
    int v = (t < SCAN_B) ? bsum[t] : 0;
    sh[t] = v;
    __syncthreads();
    for (int o = 1; o < 256; o <<= 1) {
        int u = (t >= o) ? sh[t - o] : 0;
        __syncthreads();
        sh[t] += u;
        __syncthreads();
    }
    bbase[t] = (t > 0) ? sh[t - 1] : 0;
}

__global__ __launch_bounds__(256) void write_offsets(const int* __restrict__ counts,
        const int* __restrict__ bbase, int* __restrict__ offsets, int* __restrict__ cursor)
{
    __shared__ int sh[256];
    int t = threadIdx.x;
    int i = blockIdx.x * 256 + t;
    int v = (i < NN) ? counts[i] : 0;
    sh[t] = v;
    __syncthreads();
    for (int o = 1; o < 256; o <<= 1) {
        int u = (t >= o) ? sh[t - o] : 0;
        __syncthreads();
        sh[t] += u;
        __syncthreads();
    }
    int excl = sh[t] - v + bbase[blockIdx.x];
    if (i < NN) { offsets[i] = excl; cursor[i] = excl; }
    if (i == NN - 1) offsets[NN] = excl + v;             // == NE
}

__global__ void scatter_kernel(const int* __restrict__ src, const int* __restrict__ dst,
                               int* __restrict__ cursor, int* __restrict__ csr_src)
{
    int e = blockIdx.x * blockDim.x + threadIdx.x;
    if (e < NE) {
        int pos = atomicAdd(&cursor[dst[e]], 1);
        csr_src[pos] = src[e];
    }
}

// ---------------------------------------------------------------------------
// Edge aggregation: 1 wave per node; lane owns dims {2l, 2l+1}; head = lane>>3.
// bf16 K/V gathers (4B/lane = 256B/row coalesced). Softmax without max-sub
// (scores are O(10), exp is fp32-safe; PyG eps is absorbed by den>=e^s terms).
// ---------------------------------------------------------------------------
template <int LAYER>
__global__ __launch_bounds__(256) void edge_aggregate(
    const ushort_t* __restrict__ Qb, const ushort_t* __restrict__ Kb,
    const ushort_t* __restrict__ Vb, const float* __restrict__ Sf,
    const int* __restrict__ offsets, const int* __restrict__ csr_src,
    const float* __restrict__ xres, const float* __restrict__ prelu_w,
    float* __restrict__ outF, ushort_t* __restrict__ outB)
{
    const int lane = threadIdx.x & 63;
    const int node = blockIdx.x * 4 + (threadIdx.x >> 6);   // NN % 4 == 0
    const int d2 = lane * 2;

    unsigned qu = *reinterpret_cast<const unsigned*>(Qb + (size_t)node * HID + d2);
    const float q0 = bf2f((ushort_t)(qu & 0xffff)) * 0.25f;  // fold 1/sqrt(16)
    const float q1 = bf2f((ushort_t)(qu >> 16)) * 0.25f;

    float den = 0.f, a0 = 0.f, a1 = 0.f;
    const int beg = offsets[node], end = offsets[node + 1];
    for (int i = beg; i < end; ++i) {
        int s = csr_src[i];
        unsigned ku = *reinterpret_cast<const unsigned*>(Kb + (size_t)s * HID + d2);
        float p = q0 * bf2f((ushort_t)(ku & 0xffff)) + q1 * bf2f((ushort_t)(ku >> 16));
        p += __shfl_xor(p, 1);
        p += __shfl_xor(p, 2);
        p += __shfl_xor(p, 4);                              // 8-lane head reduce
        float w = __expf(p);
        unsigned vu = *reinterpret_cast<const unsigned*>(Vb + (size_t)s * HID + d2);
        den += w;
        a0 += w * bf2f((ushort_t)(vu & 0xffff));
        a1 += w * bf2f((ushort_t)(vu >> 16));
    }
    float inv = (den > 0.f) ? 1.f / den : 0.f;
    float2 sv = *reinterpret_cast<const float2*>(Sf + (size_t)node * HID + d2);
    float r0 = a0 * inv + sv.x;
    float r1 = a1 * inv + sv.y;
    if (LAYER == 2) {
        float2 xr = *reinterpret_cast<const float2*>(xres + (size_t)node * HID + d2);
        r0 += xr.x; r1 += xr.y;
    }
    const float al = prelu_w[0];
    r0 = fmaxf(r0, 0.f) + al * fminf(r0, 0.f);
    r1 = fmaxf(r1, 0.f) + al * fminf(r1, 0.f);
    if (LAYER == 1) {
        ushort2 o; o.x = f2bf(r0); o.y = f2bf(r1);
        *reinterpret_cast<ushort2*>(outB + (size_t)node * HID + d2) = o;
    } else {
        float2 o; o.x = r0; o.y = r1;
        *reinterpret_cast<float2*>(outF + (size_t)node * HID + d2) = o;
    }
}

// ---------------------------------------------------------------------------
extern "C" void kernel_launch(void* const* d_in, const int* in_sizes, int n_in,
                              void* d_out, int out_size, void* d_ws, size_t ws_size,
                              hipStream_t stream)
{
    const float* x       = (const float*)d_in[0];
    const int*   ei      = (const int*)d_in[1];
    const float* prelu_w = (const float*)d_in[2];
    const float* Wq1 = (const float*)d_in[3],  *bq1 = (const float*)d_in[4];
    const float* Wk1 = (const float*)d_in[5],  *bk1 = (const float*)d_in[6];
    const float* Wv1 = (const float*)d_in[7],  *bv1 = (const float*)d_in[8];
    const float* Ws1 = (const float*)d_in[9],  *bs1 = (const float*)d_in[10];
    const float* Wq2 = (const float*)d_in[11], *bq2 = (const float*)d_in[12];
    const float* Wk2 = (const float*)d_in[13], *bk2 = (const float*)d_in[14];
    const float* Wv2 = (const float*)d_in[15], *bv2 = (const float*)d_in[16];
    const float* Ws2 = (const float*)d_in[17], *bs2 = (const float*)d_in[18];

    char* w = (char*)d_ws;
    size_t off = 0;
    auto alloc = [&](size_t bytes) { void* p = w + off; off += (bytes + 255) & ~(size_t)255; return p; };
    ushort_t* Xb   = (ushort_t*)alloc((size_t)NN * HID * 2);    // 12.8 MB
    ushort_t* x1b  = (ushort_t*)alloc((size_t)NN * HID * 2);
    ushort_t* Qb   = (ushort_t*)alloc((size_t)NN * HID * 2);
    ushort_t* Kb   = (ushort_t*)alloc((size_t)NN * HID * 2);
    ushort_t* Vb   = (ushort_t*)alloc((size_t)NN * HID * 2);
    float*    Sf   = (float*)alloc((size_t)NN * HID * 4);       // 25.6 MB
    ushort_t* Bt1  = (ushort_t*)alloc((size_t)512 * 128 * 2);
    ushort_t* Bt2  = (ushort_t*)alloc((size_t)512 * 128 * 2);
    int* counts  = (int*)alloc(NN * sizeof(int));
    int* bsum    = (int*)alloc(256 * sizeof(int));
    int* bbase   = (int*)alloc(256 * sizeof(int));
    int* offsets = (int*)alloc((NN + 1) * sizeof(int));
    int* cursor  = (int*)alloc(NN * sizeof(int));
    int* csr_src = (int*)alloc(NE * sizeof(int));
    (void)ws_size; (void)in_sizes; (void)n_in; (void)out_size;

    const int* srcIdx = ei;
    const int* dstIdx = ei + NE;

    // CSR build (shared by both layers)
    zero_i32<<<(NN + 255) / 256, 256, 0, stream>>>(counts, NN);
    hist_kernel<<<(NE + 255) / 256, 256, 0, stream>>>(dstIdx, counts);
    block_sums<<<SCAN_B, 256, 0, stream>>>(counts, bsum);
    scan_bsums<<<1, 256, 0, stream>>>(bsum, bbase);
    write_offsets<<<SCAN_B, 256, 0, stream>>>(counts, bbase, offsets, cursor);
    scatter_kernel<<<(NE + 255) / 256, 256, 0, stream>>>(srcIdx, dstIdx, cursor, csr_src);

    // bf16 conversions
    convert_x<<<(NN * HID / 4 + 255) / 256, 256, 0, stream>>>(x, Xb);
    pack_w<<<256, 256, 0, stream>>>(Wq1, Wk1, Wv1, Ws1, Bt1);
    pack_w<<<256, 256, 0, stream>>>(Wq2, Wk2, Wv2, Ws2, Bt2);

    dim3 ggemm((NN + 63) / 64, 4);

    // ---- layer 1 ----
    gemm_mfma<<<ggemm, 256, 0, stream>>>(Xb, Bt1, bq1, bk1, bv1, bs1, Qb, Kb, Vb, Sf);
    edge_aggregate<1><<<NN / 4, 256, 0, stream>>>(Qb, Kb, Vb, Sf, offsets, csr_src,
                                                  nullptr, prelu_w, nullptr, x1b);
    // ---- layer 2 ----
    gemm_mfma<<<ggemm, 256, 0, stream>>>(x1b, Bt2, bq2, bk2, bv2, bs2, Qb, Kb, Vb, Sf);
    edge_aggregate<2><<<NN / 4, 256, 0, stream>>>(Qb, Kb, Vb, Sf, offsets, csr_src,
                                                  x, prelu_w, (float*)d_out, nullptr);
}

// Round 3
// 224.213 us; speedup vs baseline: 3.1246x; 1.3307x over previous
//
#include <hip/hip_runtime.h>

#define NN 50000
#define NE 500000
#define HID 128

typedef __attribute__((ext_vector_type(8))) short short8;   // 8 bf16 = 16B
typedef __attribute__((ext_vector_type(4))) float f32x4;
typedef unsigned short ushort_t;

__device__ __forceinline__ float bf2f(ushort_t u) {
    union { float f; unsigned i; } x; x.i = ((unsigned)u) << 16; return x.f;
}
__device__ __forceinline__ ushort_t f2bf(float f) {
    union { float f; unsigned i; } x; x.f = f;
    unsigned r = x.i + 0x7FFFu + ((x.i >> 16) & 1u);   // RNE (no NaN inputs)
    return (ushort_t)(r >> 16);
}

// ---------------------------------------------------------------------------
// fp32 -> bf16 conversions
// ---------------------------------------------------------------------------
__global__ void convert_x(const float* __restrict__ X, ushort_t* __restrict__ Xb)
{
    int i = blockIdx.x * blockDim.x + threadIdx.x;       // one thread per 4 elems
    float4 v = *reinterpret_cast<const float4*>(X + (size_t)i * 4);
    ushort4 o;
    o.x = f2bf(v.x); o.y = f2bf(v.y); o.z = f2bf(v.z); o.w = f2bf(v.w);
    *reinterpret_cast<ushort4*>(Xb + (size_t)i * 4) = o;
}

// Bt[col][k] = W_(col/128)[k][col%128], bf16. 512x128.
__global__ void pack_w(const float* __restrict__ Wq, const float* __restrict__ Wk,
                       const float* __restrict__ Wv, const float* __restrict__ Ws,
                       ushort_t* __restrict__ Bt)
{
    int idx = blockIdx.x * 256 + threadIdx.x;            // 65536 total
    int col = idx >> 7;
    int k   = idx & 127;
    const float* W = (col < 128) ? Wq : (col < 256) ? Wk : (col < 384) ? Wv : Ws;
    Bt[idx] = f2bf(W[k * HID + (col & 127)]);
}

// ---------------------------------------------------------------------------
// MFMA GEMM: one block per 64-row tile; loops over the 4 weight groups.
// A staged once (16KB swizzled); B restaged per group (32KB swizzled);
// epilogue rearranged through LDS (Cs = Bs reused) for coalesced 16B stores.
// ---------------------------------------------------------------------------
__global__ __launch_bounds__(256) void gemm_mfma(
    const ushort_t* __restrict__ Xb, const ushort_t* __restrict__ Bt,
    const float* __restrict__ bqp, const float* __restrict__ bkp,
    const float* __restrict__ bvp, const float* __restrict__ bsp,
    ushort_t* __restrict__ Qb, ushort_t* __restrict__ Kb,
    ushort_t* __restrict__ Vb, float* __restrict__ Sf)
{
    __shared__ ushort_t As[64 * 128];    // 16KB
    __shared__ ushort_t Bs[128 * 128];   // 32KB (reused as fp32 C-tile)
    const int Mbase = blockIdx.x * 64;
    const int tid = threadIdx.x;
    const int lane = tid & 63, wave = tid >> 6;
    const int wrow = wave * 16;
    const int l15 = lane & 15;

    #pragma unroll
    for (int it = 0; it < 4; ++it) {                     // A: 1024 x 16B segs
        int lin = it * 256 + tid;
        int row = lin >> 4, s = lin & 15;
        int rg = Mbase + row; if (rg >= NN) rg = NN - 1;
        short8 v = *reinterpret_cast<const short8*>(Xb + (size_t)rg * HID + s * 8);
        *reinterpret_cast<short8*>((char*)As + row * 256 + ((s * 16) ^ ((row & 7) * 16))) = v;
    }

    for (int g = 0; g < 4; ++g) {
        #pragma unroll
        for (int it = 0; it < 8; ++it) {                 // B: 2048 x 16B segs
            int lin = it * 256 + tid;
            int col = lin >> 4, s = lin & 15;
            short8 v = *reinterpret_cast<const short8*>(Bt + (size_t)(g * 128 + col) * HID + s * 8);
            *reinterpret_cast<short8*>((char*)Bs + col * 256 + ((s * 16) ^ ((col & 7) * 16))) = v;
        }
        __syncthreads();

        f32x4 acc[8] = {};
        #pragma unroll
        for (int kk = 0; kk < 4; ++kk) {
            int kbyte = kk * 64 + (lane >> 4) * 16;      // 16B of 8 bf16, contiguous K
            int ar = wrow + l15;
            short8 a = *reinterpret_cast<const short8*>(
                (const char*)As + ar * 256 + (kbyte ^ ((ar & 7) * 16)));
            #pragma unroll
            for (int nb = 0; nb < 8; ++nb) {
                int c = nb * 16 + l15;
                short8 b = *reinterpret_cast<const short8*>(
                    (const char*)Bs + c * 256 + (kbyte ^ ((c & 7) * 16)));
                acc[nb] = __builtin_amdgcn_mfma_f32_16x16x32_bf16(a, b, acc[nb], 0, 0, 0);
            }
        }
        __syncthreads();                                 // done reading Bs

        // acc (+bias) -> LDS fp32 C-tile
        const float* bias = (g == 0) ? bqp : (g == 1) ? bkp : (g == 2) ? bvp : bsp;
        float* Cs = reinterpret_cast<float*>(Bs);
        #pragma unroll
        for (int nb = 0; nb < 8; ++nb) {
            int c = nb * 16 + l15;
            float bb = bias[c];
            #pragma unroll
            for (int r = 0; r < 4; ++r) {
                int rl = wrow + (lane >> 4) * 4 + r;     // C/D: col=lane&15, row=(lane>>4)*4+reg
                Cs[rl * 128 + c] = acc[nb][r] + bb;
            }
        }
        __syncthreads();

        // LDS -> coalesced global stores
        if (g == 3) {
            #pragma unroll
            for (int it = 0; it < 4; ++it) {
                int lin = it * 256 + tid;
                int row = lin >> 4, c8 = (lin & 15) * 8;
                int rg = Mbase + row;
                if (rg < NN) {
                    float4 v0 = *reinterpret_cast<float4*>(&Cs[row * 128 + c8]);
                    float4 v1 = *reinterpret_cast<float4*>(&Cs[row * 128 + c8 + 4]);
                    *reinterpret_cast<float4*>(&Sf[(size_t)rg * HID + c8]) = v0;
                    *reinterpret_cast<float4*>(&Sf[(size_t)rg * HID + c8 + 4]) = v1;
                }
            }
        } else {
            ushort_t* Ob = (g == 0) ? Qb : (g == 1) ? Kb : Vb;
            #pragma unroll
            for (int it = 0; it < 4; ++it) {
                int lin = it * 256 + tid;
                int row = lin >> 4, c8 = (lin & 15) * 8;
                int rg = Mbase + row;
                if (rg < NN) {
                    float4 v0 = *reinterpret_cast<float4*>(&Cs[row * 128 + c8]);
                    float4 v1 = *reinterpret_cast<float4*>(&Cs[row * 128 + c8 + 4]);
                    short8 o;
                    o[0] = (short)f2bf(v0.x); o[1] = (short)f2bf(v0.y);
                    o[2] = (short)f2bf(v0.z); o[3] = (short)f2bf(v0.w);
                    o[4] = (short)f2bf(v1.x); o[5] = (short)f2bf(v1.y);
                    o[6] = (short)f2bf(v1.z); o[7] = (short)f2bf(v1.w);
                    *reinterpret_cast<short8*>(&Ob[(size_t)rg * HID + c8]) = o;
                }
            }
        }
        __syncthreads();                                 // before restaging Bs
    }
}

// ---------------------------------------------------------------------------
// CSR build
// ---------------------------------------------------------------------------
__global__ void zero_i32(int* __restrict__ p, int n)
{
    int i = blockIdx.x * blockDim.x + threadIdx.x;
    if (i < n) p[i] = 0;
}

__global__ void hist_kernel(const int* __restrict__ dst, int* __restrict__ counts)
{
    int e = blockIdx.x * blockDim.x + threadIdx.x;
    if (e < NE) atomicAdd(&counts[dst[e]], 1);
}

#define SCAN_B 196   // ceil(NN/256)

__global__ __launch_bounds__(256) void block_sums(const int* __restrict__ counts,
                                                  int* __restrict__ bsum)
{
    int i = blockIdx.x * 256 + threadIdx.x;
    int v = (i < NN) ? counts[i] : 0;
    #pragma unroll
    for (int o = 1; o < 64; o <<= 1) v += __shfl_xor(v, o);
    __shared__ int ws[4];
    if ((threadIdx.x & 63) == 0) ws[threadIdx.x >> 6] = v;
    __syncthreads();
    if (threadIdx.x == 0) bsum[blockIdx.x] = ws[0] + ws[1] + ws[2] + ws[3];
}

__global__ __launch_bounds__(256) void scan_bsums(const int* __restrict__ bsum,
                                                  int* __restrict__ bbase)
{
    __shared__ int sh[256];
    int t = threadIdx.x;
    int v = (t < SCAN_B) ? bsum[t] : 0;
    sh[t] = v;
    __syncthreads();
    for (int o = 1; o < 256; o <<= 1) {
        int u = (t >= o) ? sh[t - o] : 0;
        __syncthreads();
        sh[t] += u;
        __syncthreads();
    }
    bbase[t] = (t > 0) ? sh[t - 1] : 0;
}

__global__ __launch_bounds__(256) void write_offsets(const int* __restrict__ counts,
        const int* __restrict__ bbase, int* __restrict__ offsets, int* __restrict__ cursor)
{
    __shared__ int sh[256];
    int t = threadIdx.x;
    int i = blockIdx.x * 256 + t;
    int v = (i < NN) ? counts[i] : 0;
    sh[t] = v;
    __syncthreads();
    for (int o = 1; o < 256; o <<= 1) {
        int u = (t >= o) ? sh[t - o] : 0;
        __syncthreads();
        sh[t] += u;
        __syncthreads();
    }
    int excl = sh[t] - v + bbase[blockIdx.x];
    if (i < NN) { offsets[i] = excl; cursor[i] = excl; }
    if (i == NN - 1) offsets[NN] = excl + v;             // == NE
}

__global__ void scatter_kernel(const int* __restrict__ src, const int* __restrict__ dst,
                               int* __restrict__ cursor, int* __restrict__ csr_src)
{
    int e = blockIdx.x * blockDim.x + threadIdx.x;
    if (e < NE) {
        int pos = atomicAdd(&cursor[dst[e]], 1);
        csr_src[pos] = src[e];
    }
}

// ---------------------------------------------------------------------------
// Edge aggregation: 1 wave per node; half-wave per edge (2 edges/iteration,
// unrolled x2 => 4 K-rows + 4 V-rows in flight). Lane owns 4 dims (8B loads).
// Head = 16 dims = 4 lanes -> shfl_xor(1,2) reduce. Softmax without max-sub.
// ---------------------------------------------------------------------------
template <int LAYER>
__global__ __launch_bounds__(256) void edge_aggregate(
    const ushort_t* __restrict__ Qb, const ushort_t* __restrict__ Kb,
    const ushort_t* __restrict__ Vb, const float* __restrict__ Sf,
    const int* __restrict__ offsets, const int* __restrict__ csr_src,
    const float* __restrict__ xres, const float* __restrict__ prelu_w,
    float* __restrict__ outF, ushort_t* __restrict__ outB)
{
    const int lane = threadIdx.x & 63;
    const int node = blockIdx.x * 4 + (threadIdx.x >> 6);   // NN % 4 == 0
    const int half = lane >> 5;
    const int l5   = lane & 31;
    const int d4   = l5 * 4;

    ushort4 qu = *reinterpret_cast<const ushort4*>(Qb + (size_t)node * HID + d4);
    const float q0 = bf2f(qu.x) * 0.25f, q1 = bf2f(qu.y) * 0.25f;
    const float q2 = bf2f(qu.z) * 0.25f, q3 = bf2f(qu.w) * 0.25f;

    float den = 0.f, a0 = 0.f, a1 = 0.f, a2 = 0.f, a3 = 0.f;
    const int beg = offsets[node], end = offsets[node + 1];
    int i = beg;
    for (; i + 4 <= end; i += 4) {
        int sA = csr_src[i + half];
        int sB = csr_src[i + 2 + half];
        ushort4 kA = *reinterpret_cast<const ushort4*>(Kb + (size_t)sA * HID + d4);
        ushort4 kB = *reinterpret_cast<const ushort4*>(Kb + (size_t)sB * HID + d4);
        ushort4 vA = *reinterpret_cast<const ushort4*>(Vb + (size_t)sA * HID + d4);
        ushort4 vB = *reinterpret_cast<const ushort4*>(Vb + (size_t)sB * HID + d4);
        float pA = q0 * bf2f(kA.x) + q1 * bf2f(kA.y) + q2 * bf2f(kA.z) + q3 * bf2f(kA.w);
        float pB = q0 * bf2f(kB.x) + q1 * bf2f(kB.y) + q2 * bf2f(kB.z) + q3 * bf2f(kB.w);
        pA += __shfl_xor(pA, 1); pA += __shfl_xor(pA, 2);
        pB += __shfl_xor(pB, 1); pB += __shfl_xor(pB, 2);
        float wA = __expf(pA);
        float wB = __expf(pB);
        den += wA + wB;
        a0 += wA * bf2f(vA.x) + wB * bf2f(vB.x);
        a1 += wA * bf2f(vA.y) + wB * bf2f(vB.y);
        a2 += wA * bf2f(vA.z) + wB * bf2f(vB.z);
        a3 += wA * bf2f(vA.w) + wB * bf2f(vB.w);
    }
    for (; i < end; i += 2) {
        int myi = i + half;
        int s = csr_src[myi < end ? myi : end - 1];
        ushort4 ku = *reinterpret_cast<const ushort4*>(Kb + (size_t)s * HID + d4);
        ushort4 vu = *reinterpret_cast<const ushort4*>(Vb + (size_t)s * HID + d4);
        float p = q0 * bf2f(ku.x) + q1 * bf2f(ku.y) + q2 * bf2f(ku.z) + q3 * bf2f(ku.w);
        p += __shfl_xor(p, 1); p += __shfl_xor(p, 2);
        float w = (myi < end) ? __expf(p) : 0.f;
        den += w;
        a0 += w * bf2f(vu.x); a1 += w * bf2f(vu.y);
        a2 += w * bf2f(vu.z); a3 += w * bf2f(vu.w);
    }
    // combine the two half-waves
    den += __shfl_xor(den, 32);
    a0 += __shfl_xor(a0, 32); a1 += __shfl_xor(a1, 32);
    a2 += __shfl_xor(a2, 32); a3 += __shfl_xor(a3, 32);

    if (half == 0) {
        float inv = (den > 0.f) ? 1.f / den : 0.f;
        float4 sv = *reinterpret_cast<const float4*>(Sf + (size_t)node * HID + d4);
        float r0 = a0 * inv + sv.x;
        float r1 = a1 * inv + sv.y;
        float r2 = a2 * inv + sv.z;
        float r3 = a3 * inv + sv.w;
        if (LAYER == 2) {
            float4 xr = *reinterpret_cast<const float4*>(xres + (size_t)node * HID + d4);
            r0 += xr.x; r1 += xr.y; r2 += xr.z; r3 += xr.w;
        }
        const float al = prelu_w[0];
        r0 = fmaxf(r0, 0.f) + al * fminf(r0, 0.f);
        r1 = fmaxf(r1, 0.f) + al * fminf(r1, 0.f);
        r2 = fmaxf(r2, 0.f) + al * fminf(r2, 0.f);
        r3 = fmaxf(r3, 0.f) + al * fminf(r3, 0.f);
        if (LAYER == 1) {
            ushort4 o;
            o.x = f2bf(r0); o.y = f2bf(r1); o.z = f2bf(r2); o.w = f2bf(r3);
            *reinterpret_cast<ushort4*>(outB + (size_t)node * HID + d4) = o;
        } else {
            float4 o; o.x = r0; o.y = r1; o.z = r2; o.w = r3;
            *reinterpret_cast<float4*>(outF + (size_t)node * HID + d4) = o;
        }
    }
}

// ---------------------------------------------------------------------------
extern "C" void kernel_launch(void* const* d_in, const int* in_sizes, int n_in,
                              void* d_out, int out_size, void* d_ws, size_t ws_size,
                              hipStream_t stream)
{
    const float* x       = (const float*)d_in[0];
    const int*   ei      = (const int*)d_in[1];
    const float* prelu_w = (const float*)d_in[2];
    const float* Wq1 = (const float*)d_in[3],  *bq1 = (const float*)d_in[4];
    const float* Wk1 = (const float*)d_in[5],  *bk1 = (const float*)d_in[6];
    const float* Wv1 = (const float*)d_in[7],  *bv1 = (const float*)d_in[8];
    const float* Ws1 = (const float*)d_in[9],  *bs1 = (const float*)d_in[10];
    const float* Wq2 = (const float*)d_in[11], *bq2 = (const float*)d_in[12];
    const float* Wk2 = (const float*)d_in[13], *bk2 = (const float*)d_in[14];
    const float* Wv2 = (const float*)d_in[15], *bv2 = (const float*)d_in[16];
    const float* Ws2 = (const float*)d_in[17], *bs2 = (const float*)d_in[18];

    char* w = (char*)d_ws;
    size_t off = 0;
    auto alloc = [&](size_t bytes) { void* p = w + off; off += (bytes + 255) & ~(size_t)255; return p; };
    ushort_t* Xb   = (ushort_t*)alloc((size_t)NN * HID * 2);    // 12.8 MB
    ushort_t* x1b  = (ushort_t*)alloc((size_t)NN * HID * 2);
    ushort_t* Qb   = (ushort_t*)alloc((size_t)NN * HID * 2);
    ushort_t* Kb   = (ushort_t*)alloc((size_t)NN * HID * 2);
    ushort_t* Vb   = (ushort_t*)alloc((size_t)NN * HID * 2);
    float*    Sf   = (float*)alloc((size_t)NN * HID * 4);       // 25.6 MB
    ushort_t* Bt1  = (ushort_t*)alloc((size_t)512 * 128 * 2);
    ushort_t* Bt2  = (ushort_t*)alloc((size_t)512 * 128 * 2);
    int* counts  = (int*)alloc(NN * sizeof(int));
    int* bsum    = (int*)alloc(256 * sizeof(int));
    int* bbase   = (int*)alloc(256 * sizeof(int));
    int* offsets = (int*)alloc((NN + 1) * sizeof(int));
    int* cursor  = (int*)alloc(NN * sizeof(int));
    int* csr_src = (int*)alloc(NE * sizeof(int));
    (void)ws_size; (void)in_sizes; (void)n_in; (void)out_size;

    const int* srcIdx = ei;
    const int* dstIdx = ei + NE;

    // CSR build (shared by both layers)
    zero_i32<<<(NN + 255) / 256, 256, 0, stream>>>(counts, NN);
    hist_kernel<<<(NE + 255) / 256, 256, 0, stream>>>(dstIdx, counts);
    block_sums<<<SCAN_B, 256, 0, stream>>>(counts, bsum);
    scan_bsums<<<1, 256, 0, stream>>>(bsum, bbase);
    write_offsets<<<SCAN_B, 256, 0, stream>>>(counts, bbase, offsets, cursor);
    scatter_kernel<<<(NE + 255) / 256, 256, 0, stream>>>(srcIdx, dstIdx, cursor, csr_src);

    // bf16 conversions
    convert_x<<<(NN * HID / 4 + 255) / 256, 256, 0, stream>>>(x, Xb);
    pack_w<<<256, 256, 0, stream>>>(Wq1, Wk1, Wv1, Ws1, Bt1);
    pack_w<<<256, 256, 0, stream>>>(Wq2, Wk2, Wv2, Ws2, Bt2);

    const int ggemm = (NN + 63) / 64;

    // ---- layer 1 ----
    gemm_mfma<<<ggemm, 256, 0, stream>>>(Xb, Bt1, bq1, bk1, bv1, bs1, Qb, Kb, Vb, Sf);
    edge_aggregate<1><<<NN / 4, 256, 0, stream>>>(Qb, Kb, Vb, Sf, offsets, csr_src,
                                                  nullptr, prelu_w, nullptr, x1b);
    // ---- layer 2 ----
    gemm_mfma<<<ggemm, 256, 0, stream>>>(x1b, Bt2, bq2, bk2, bv2, bs2, Qb, Kb, Vb, Sf);
    edge_aggregate<2><<<NN / 4, 256, 0, stream>>>(Qb, Kb, Vb, Sf, offsets, csr_src,
                                                  x, prelu_w, (float*)d_out, nullptr);
}